// Round 2
// 261.681 us; speedup vs baseline: 1.0114x; 1.0114x over previous
//
#include <hip/hip_runtime.h>
#include <hip/hip_bf16.h>
#include <stdint.h>

#define NUM_EMB 4096
#define EMB_DIM 256
#define NVEC 65536                     // 64*32*32
#define OUT0_SIZE (NVEC * EMB_DIM)     // z_q_ste elements; loss scalar follows
#define MTILE 128                      // z rows per block
#define NTILE 64                       // codebook entries per LDS tile
#define DCONST 0.0625f                 // positivity shift for packed distance

typedef __bf16 bf16x8 __attribute__((ext_vector_type(8)));
typedef float floatx16 __attribute__((ext_vector_type(16)));

static __device__ __forceinline__ unsigned int f2bf(float f) {
  unsigned int u = __float_as_uint(f);
  return (u + 0x7fffu + ((u >> 16) & 1u)) >> 16;  // RNE fp32->bf16
}

static __device__ __forceinline__ uint4 pack_bf8(float4 a, float4 b) {
  uint4 r;
  r.x = f2bf(a.x) | (f2bf(a.y) << 16);
  r.y = f2bf(a.z) | (f2bf(a.w) << 16);
  r.z = f2bf(b.x) | (f2bf(b.y) << 16);
  r.w = f2bf(b.z) | (f2bf(b.w) << 16);
  return r;
}

// Prep: codebook fp32 -> bf16 (ws), ||e||^2 + DCONST (ws), zero loss slot.
__global__ void __launch_bounds__(256) vq_prep(const float* __restrict__ cbf,
                                               unsigned short* __restrict__ cbb,
                                               float* __restrict__ enorm,
                                               float* __restrict__ out) {
  int w = threadIdx.x >> 6;
  int lane = threadIdx.x & 63;
  int row = blockIdx.x * 4 + w;
  float4 v = ((const float4*)(cbf + (size_t)row * EMB_DIM))[lane];
  float ss = v.x * v.x + v.y * v.y + v.z * v.z + v.w * v.w;
  ushort4 b;
  b.x = (unsigned short)f2bf(v.x);
  b.y = (unsigned short)f2bf(v.y);
  b.z = (unsigned short)f2bf(v.z);
  b.w = (unsigned short)f2bf(v.w);
  ((ushort4*)(cbb + (size_t)row * EMB_DIM))[lane] = b;
#pragma unroll
  for (int m = 1; m < 64; m <<= 1) ss += __shfl_xor(ss, m, 64);
  if (lane == 0) enorm[row] = ss + DCONST;
  if (blockIdx.x == 0 && threadIdx.x == 0) out[OUT0_SIZE] = 0.0f;
}

// Main: distance-GEMM with double-buffered async LDS staging (global_load_lds
// DMA issued a full compute-phase early, one barrier/tile), XOR bank-swizzle
// on both stage-source and ds_read, packed argmin + loss + gather.
__global__ void __launch_bounds__(256, 2) vq_main(const float* __restrict__ z,
                                                  const float* __restrict__ cbf,
                                                  const unsigned short* __restrict__ cbb,
                                                  const float* __restrict__ enorm,
                                                  float* __restrict__ out) {
  __shared__ __align__(16) unsigned char sstage[2][NTILE * 512];  // 64 KB dbuf
  __shared__ unsigned int minlds[2][MTILE];
  __shared__ int idx_lds[MTILE];
  __shared__ float wsum[4];
  __shared__ float zwsum[2];

  const int t = threadIdx.x;
  const int w = t >> 6;
  const int lane = t & 63;
  const int h = lane >> 5;     // half-wave
  const int eL = lane & 31;
  const int rg = w & 1;        // row group: rows rg*64..+63 of the block tile
  const int cg = w >> 1;       // col group: cols cg*32..+31 of each 64-entry tile
  const int blk = blockIdx.x;
  const int row_base = blk * MTILE + rg * 64;

  // Async DMA of one 64x256 bf16 codebook tile into sstage[buf].
  // LDS dest is linear (wave-uniform base + lane*16); the bank swizzle is
  // applied by permuting the GLOBAL source 16B-slot: s ^= (entry & 7).
  auto stage_tile = [&](int buf, int c0) {
#pragma unroll
    for (int j = 0; j < 8; ++j) {
      int e = (w << 4) + (j << 1) + h;          // entry within tile
      int s = eL ^ (e & 7);                     // swizzled source slot
      const unsigned short* src = cbb + ((size_t)(c0 + e) << 8) + (s << 3);
      __builtin_amdgcn_global_load_lds(
          (const __attribute__((address_space(1))) void*)src,
          (__attribute__((address_space(3))) void*)&sstage[buf][(w << 13) + (j << 10)],
          16, 0, 0);
    }
  };

  // Kick off tile 0 DMA before the A-phase so its latency hides under z loads.
  stage_tile(0, 0);
  float enC = enorm[cg * 32 + eL];

  // ---- A-phase: 64 z rows (2 groups of 32) x D=256 as bf16 into registers.
  // A layout for 32x32x16: m = lane&31, k = (lane>>5)*8 + j, per 16-k step.
  uint4 afrag[2][16];
  float zn[2] = {0.f, 0.f};
#pragma unroll
  for (int g = 0; g < 2; ++g) {
    const float* rp = z + (size_t)(row_base + g * 32 + eL) * EMB_DIM + h * 8;
#pragma unroll
    for (int ks = 0; ks < 16; ++ks) {
      float4 a0 = *(const float4*)(rp + ks * 16);
      float4 a1 = *(const float4*)(rp + ks * 16 + 4);
      zn[g] += a0.x * a0.x + a0.y * a0.y + a0.z * a0.z + a0.w * a0.w
             + a1.x * a1.x + a1.y * a1.y + a1.z * a1.z + a1.w * a1.w;
      afrag[g][ks] = pack_bf8(a0, a1);
    }
    zn[g] += __shfl_xor(zn[g], 32, 64);
  }
  // Sum ||z||^2 over this wave's 64 rows (waves with cg==0 cover all 128 rows).
  if (cg == 0) {
    float zs = zn[0] + zn[1];
#pragma unroll
    for (int m = 1; m <= 16; m <<= 1) zs += __shfl_xor(zs, m, 64);
    if (lane == 0) zwsum[rg] = zs;
  }

  // Running packed argmin: top-20 bits of positive distance | 12-bit col.
  unsigned int pmin[32];
#pragma unroll
  for (int s = 0; s < 32; ++s) pmin[s] = 0xFFFFFFFFu;

  __syncthreads();  // drains vmcnt: tile-0 DMA + A loads complete

  const int sx4 = (eL & 7) << 4;  // read-side slot swizzle (matches stage)
  int cur = 0;
  for (int c0 = 0; c0 < NUM_EMB; c0 += NTILE) {
    // Prefetch tile t+1 into the other buffer; lands during this compute.
    int c1 = c0 + NTILE;
    float enN = enC;
    if (c1 < NUM_EMB) {
      stage_tile(cur ^ 1, c1);
      enN = enorm[c1 + cg * 32 + eL];
    }

    // Wave handles its 32-col half: 16 k-steps, B-frag reused by 2 row groups.
    floatx16 acc0, acc1;
#pragma unroll
    for (int r = 0; r < 16; ++r) { acc0[r] = 0.f; acc1[r] = 0.f; }
    const unsigned char* bp = &sstage[cur][(cg * 32 + eL) * 512];
#pragma unroll
    for (int ks = 0; ks < 16; ++ks) {
      uint4 bv = *(const uint4*)(bp + ((ks * 32 + h * 16) ^ sx4));
      bf16x8 b = __builtin_bit_cast(bf16x8, bv);
      acc0 = __builtin_amdgcn_mfma_f32_32x32x16_bf16(
          __builtin_bit_cast(bf16x8, afrag[0][ks]), b, acc0, 0, 0, 0);
      acc1 = __builtin_amdgcn_mfma_f32_32x32x16_bf16(
          __builtin_bit_cast(bf16x8, afrag[1][ks]), b, acc1, 0, 0, 0);
    }

    // d = -2*(z.e) + (||e||^2 + C) > 0; pack top-20 bits with col index.
    unsigned int colb = (unsigned int)(c0 + cg * 32 + eL);
#pragma unroll
    for (int reg = 0; reg < 16; ++reg) {
      float d0 = fmaf(-2.f, acc0[reg], enC);
      unsigned int p0 = (__float_as_uint(d0) & 0xFFFFF000u) | colb;
      if (p0 < pmin[reg]) pmin[reg] = p0;
      float d1 = fmaf(-2.f, acc1[reg], enC);
      unsigned int p1 = (__float_as_uint(d1) & 0xFFFFF000u) | colb;
      if (p1 < pmin[16 + reg]) pmin[16 + reg] = p1;
    }

    __syncthreads();  // single barrier/tile: drains next-tile DMA (vmcnt(0))
    cur ^= 1;
    enC = enN;
  }

  // Reduce over the 32 col-lanes (xor 1..16 stays within half-wave; halves
  // cover disjoint row sets). Packed u32 min = (distance, index) lexicographic
  // -> smallest-index tiebreak like np.argmin.
#pragma unroll
  for (int s = 0; s < 32; ++s) {
    unsigned int v = pmin[s];
#pragma unroll
    for (int m = 1; m <= 16; m <<= 1) {
      unsigned int o = __shfl_xor(v, m, 64);
      if (o < v) v = o;
    }
    pmin[s] = v;
  }
  // C/D layout 32x32: row = (reg&3) + 8*(reg>>2) + 4*(lane>>5), col = lane&31.
  if (eL == 0) {
#pragma unroll
    for (int s = 0; s < 32; ++s) {
      int g = s >> 4, reg = s & 15;
      int rowl = rg * 64 + g * 32 + (reg & 3) + 8 * (reg >> 2) + 4 * h;
      minlds[cg][rowl] = pmin[s];
    }
  }
  __syncthreads();

  // Combine col-halves; recover idx + distance; loss = sum(||z||^2 + d - C).
  float rl = 0.f;
  if (t < MTILE) {
    unsigned int m0 = minlds[0][t], m1 = minlds[1][t];
    unsigned int m = m1 < m0 ? m1 : m0;
    idx_lds[t] = (int)(m & 0xFFFu);
    rl = __uint_as_float(m & 0xFFFFF000u) - DCONST;
  }
#pragma unroll
  for (int m = 1; m < 64; m <<= 1) rl += __shfl_xor(rl, m, 64);
  if (lane == 0) wsum[w] = rl;
  __syncthreads();
  if (t == 0) {
    float s = (wsum[0] + wsum[1]) + (wsum[2] + wsum[3]) + zwsum[0] + zwsum[1];
    atomicAdd(out + OUT0_SIZE, s * (1.25f / (float)OUT0_SIZE));
  }

  // Gather phase: out = codebook[idx] (== z + (z_q - z) to ~3e-7).
#pragma unroll 4
  for (int j = 0; j < 32; ++j) {
    int id4 = j * 256 + t;     // float4 index within 128x256 tile
    int r = id4 >> 6, c4 = id4 & 63;
    int k = idx_lds[r];
    float4 ev = ((const float4*)(cbf + (size_t)k * EMB_DIM))[c4];
    ((float4*)(out + (size_t)(blk * MTILE + r) * EMB_DIM))[c4] = ev;
  }
}

extern "C" void kernel_launch(void* const* d_in, const int* in_sizes, int n_in,
                              void* d_out, int out_size, void* d_ws, size_t ws_size,
                              hipStream_t stream) {
  const float* z = (const float*)d_in[0];
  const float* cbf = (const float*)d_in[1];
  unsigned short* cbb = (unsigned short*)d_ws;                           // 2 MB bf16 codebook
  float* enorm = (float*)((char*)d_ws + (size_t)NUM_EMB * EMB_DIM * 2);  // +16 KB
  float* out = (float*)d_out;
  vq_prep<<<NUM_EMB / 4, 256, 0, stream>>>(cbf, cbb, enorm, out);
  vq_main<<<NVEC / MTILE, 256, 0, stream>>>(z, cbf, cbb, enorm, out);
}